// Round 1
// baseline (4415.056 us; speedup 1.0000x reference)
//
#include <hip/hip_runtime.h>
#include <stdint.h>

#define NDRUG 20000
#define NDIS  40000
#define DIN   256
#define HID   128
#define NE    150000
#define NREL  7

// ---------- helpers: total-order float <-> uint encoding for atomic max ----------
__device__ __forceinline__ unsigned enc_f(float f) {
  unsigned b = __float_as_uint(f);
  return (b & 0x80000000u) ? ~b : (b | 0x80000000u);
}
__device__ __forceinline__ float dec_f(unsigned u) {
  unsigned b = (u & 0x80000000u) ? (u ^ 0x80000000u) : ~u;
  return __uint_as_float(b);
}
#define ENC_NEG_INF 0x007FFFFFu  // enc_f(-inf)

// ---------- GEMM: C[M,128] = A[M,K] @ W[K,128] (+bias, +relu) ----------
template<int K, bool BIAS, bool RELU>
__global__ __launch_bounds__(256) void gemm128(const float* __restrict__ A,
                                               const float* __restrict__ W,
                                               const float* __restrict__ bias,
                                               float* __restrict__ C, int M)
{
  __shared__ float As[32][65];    // A tile transposed [k][row], +1 pad
  __shared__ float Bs[32][128];   // W tile [k][col]
  const int tid = threadIdx.x;
  const int m0  = blockIdx.x * 64;
  const int tr  = tid >> 5;   // 0..7 row-group
  const int tc  = tid & 31;   // 0..31 col-group
  float acc[8][4] = {};

  for (int k0 = 0; k0 < K; k0 += 32) {
    // load A tile: 64x32 floats, 2 float4 per thread
    #pragma unroll
    for (int i = 0; i < 2; ++i) {
      int f = tid + 256 * i;
      int row = f >> 3, kk = (f & 7) << 2;
      float4 v = make_float4(0.f, 0.f, 0.f, 0.f);
      int gr = m0 + row;
      if (gr < M) v = *reinterpret_cast<const float4*>(A + (size_t)gr * K + k0 + kk);
      As[kk + 0][row] = v.x; As[kk + 1][row] = v.y;
      As[kk + 2][row] = v.z; As[kk + 3][row] = v.w;
    }
    // load W tile: 32x128 floats, 4 float4 per thread
    #pragma unroll
    for (int i = 0; i < 4; ++i) {
      int f = tid + 256 * i;
      int wr = f >> 5, wc = (f & 31) << 2;
      *reinterpret_cast<float4*>(&Bs[wr][wc]) =
          *reinterpret_cast<const float4*>(W + (size_t)(k0 + wr) * HID + wc);
    }
    __syncthreads();
    #pragma unroll
    for (int k = 0; k < 32; ++k) {
      float a[8];
      #pragma unroll
      for (int i = 0; i < 8; ++i) a[i] = As[k][tr * 8 + i];
      const float4 b4 = *reinterpret_cast<const float4*>(&Bs[k][tc * 4]);
      const float bb[4] = {b4.x, b4.y, b4.z, b4.w};
      #pragma unroll
      for (int i = 0; i < 8; ++i)
        #pragma unroll
        for (int j = 0; j < 4; ++j)
          acc[i][j] += a[i] * bb[j];
    }
    __syncthreads();
  }

  float4 bv = make_float4(0.f, 0.f, 0.f, 0.f);
  if (BIAS) bv = *reinterpret_cast<const float4*>(bias + tc * 4);
  #pragma unroll
  for (int i = 0; i < 8; ++i) {
    int gr = m0 + tr * 8 + i;
    if (gr >= M) continue;
    float4 v = make_float4(acc[i][0], acc[i][1], acc[i][2], acc[i][3]);
    if (BIAS) { v.x += bv.x; v.y += bv.y; v.z += bv.z; v.w += bv.w; }
    if (RELU) {
      v.x = fmaxf(v.x, 0.f); v.y = fmaxf(v.y, 0.f);
      v.z = fmaxf(v.z, 0.f); v.w = fmaxf(v.w, 0.f);
    }
    *reinterpret_cast<float4*>(C + (size_t)gr * HID + tc * 4) = v;
  }
}

// ---------- wvec: w[slot][k] = sum_j W[r][k][j] * a[r][j]  (slot<7: src, else dst) ----------
__global__ void wvec_kernel(const float* __restrict__ Wsrc, const float* __restrict__ as_,
                            const float* __restrict__ Wdst, const float* __restrict__ ad_,
                            float* __restrict__ wv, int K)
{
  int slot = blockIdx.x;   // 0..13
  int r = slot % NREL;
  const float* W = (slot < NREL ? Wsrc : Wdst) + (size_t)r * K * HID;
  const float* a = (slot < NREL ? as_ : ad_) + r * HID;
  __shared__ float sa[HID];
  if (threadIdx.x < HID) sa[threadIdx.x] = a[threadIdx.x];
  __syncthreads();
  for (int k = threadIdx.x; k < K; k += blockDim.x) {
    const float* wr = W + (size_t)k * HID;
    float s = 0.f;
    #pragma unroll 4
    for (int j = 0; j < HID; ++j) s += wr[j] * sa[j];
    wv[slot * 256 + k] = s;
  }
}

// ---------- batched GEMV: alpha[v][i] = dot(X[i], wv[slot_v]) ----------
struct AlphaJobs { int wslot[8]; int outOff[8]; };

template<int NV, int K>
__global__ __launch_bounds__(256) void alpha_batch(const float* __restrict__ X, int N,
                                                   const float* __restrict__ wv,
                                                   float* __restrict__ outBase, AlphaJobs jobs)
{
  int i = blockIdx.x * blockDim.x + threadIdx.x;
  if (i >= N) return;
  float acc[NV];
  #pragma unroll
  for (int v = 0; v < NV; ++v) acc[v] = 0.f;
  const float* xp = X + (size_t)i * K;
  #pragma unroll 4
  for (int k = 0; k < K; k += 4) {
    float4 x = *reinterpret_cast<const float4*>(xp + k);
    #pragma unroll
    for (int v = 0; v < NV; ++v) {
      const float4 w = *reinterpret_cast<const float4*>(wv + jobs.wslot[v] * 256 + k);
      acc[v] += x.x * w.x + x.y * w.y + x.z * w.z + x.w * w.w;
    }
  }
  #pragma unroll
  for (int v = 0; v < NV; ++v) outBase[jobs.outOff[v] + i] = acc[v];
}

// ---------- edge kernels ----------
struct RelIdx { const int* src[NREL]; const int* dst[NREL]; };

__global__ void init_md(unsigned* __restrict__ amax, float* __restrict__ denom) {
  int i = blockIdx.x * blockDim.x + threadIdx.x;
  if (i < NREL * NDIS) { amax[i] = ENC_NEG_INF; denom[i] = 0.f; }
}

__global__ void init_out(float* __restrict__ out, int N, const float* __restrict__ b, int mask) {
  __shared__ float sb[HID];
  if (threadIdx.x < HID) {
    float s = 0.f;
    for (int r = 0; r < NREL; ++r)
      if (mask & (1 << r)) s += b[r * HID + threadIdx.x];
    sb[threadIdx.x] = s;
  }
  __syncthreads();
  int total = N * (HID / 4);
  for (int idx = blockIdx.x * blockDim.x + threadIdx.x; idx < total;
       idx += gridDim.x * blockDim.x) {
    int j = (idx & 31) << 2;
    float4 v = make_float4(sb[j], sb[j + 1], sb[j + 2], sb[j + 3]);
    *reinterpret_cast<float4*>(out + (size_t)idx * 4) = v;
  }
}

__global__ void edge_pass1(RelIdx ri, const float* __restrict__ alphaBase,
                           unsigned* __restrict__ amax, float* __restrict__ alpha_e)
{
  int e = blockIdx.x * blockDim.x + threadIdx.x;
  int r = blockIdx.y;
  if (e >= NE) return;
  int s = ri.src[r][e], d = ri.dst[r][e];
  float a = alphaBase[r * NDIS + s] + alphaBase[(NREL + r) * NDIS + d];
  a = a > 0.f ? a : 0.2f * a;
  alpha_e[r * NE + e] = a;
  atomicMax(&amax[r * NDIS + d], enc_f(a));
}

__global__ void edge_pass2(RelIdx ri, const unsigned* __restrict__ amax,
                           float* __restrict__ alpha_e, float* __restrict__ denom)
{
  int e = blockIdx.x * blockDim.x + threadIdx.x;
  int r = blockIdx.y;
  if (e >= NE) return;
  int d = ri.dst[r][e];
  float m = dec_f(amax[r * NDIS + d]);
  float ex = __expf(alpha_e[r * NE + e] - m);
  alpha_e[r * NE + e] = ex;
  atomicAdd(&denom[r * NDIS + d], ex);
}

__global__ void edge_pass3(const int* __restrict__ src, const int* __restrict__ dst,
                           const float* __restrict__ ex_e, const float* __restrict__ denom,
                           const float* __restrict__ hs, float* __restrict__ out)
{
  int t = blockIdx.x * blockDim.x + threadIdx.x;
  int e = t >> 5;
  if (e >= NE) return;
  int j = (t & 31) << 2;
  int d = dst[e], s = src[e];
  float coef = ex_e[e] / (denom[d] + 1e-16f);
  float4 h = *reinterpret_cast<const float4*>(hs + (size_t)s * HID + j);
  float* op = out + (size_t)d * HID + j;
  atomicAdd(op + 0, h.x * coef);
  atomicAdd(op + 1, h.y * coef);
  atomicAdd(op + 2, h.z * coef);
  atomicAdd(op + 3, h.w * coef);
}

__global__ void relu_k(float* __restrict__ x, int n4) {
  for (int i = blockIdx.x * blockDim.x + threadIdx.x; i < n4; i += gridDim.x * blockDim.x) {
    float4 v = *reinterpret_cast<float4*>(x + (size_t)i * 4);
    v.x = fmaxf(v.x, 0.f); v.y = fmaxf(v.y, 0.f);
    v.z = fmaxf(v.z, 0.f); v.w = fmaxf(v.w, 0.f);
    *reinterpret_cast<float4*>(x + (size_t)i * 4) = v;
  }
}

// ---------- host ----------
static const int SRCh[NREL] = {0, 1, 0, 1, 1, 1, 0};
static const int DSTh[NREL] = {1, 0, 1, 0, 1, 1, 0};

struct WsPlan {
  float* xd1; float* xi1; float* xd2; float* xi2;
  float* hsb; float* alphaB; float* wv;
  unsigned* amax; float* denom; float* alpha_e;
  size_t total_bytes;
};

static WsPlan plan_ws(void* d_ws) {
  WsPlan p;
  float* w = (float*)d_ws;
  p.xd1 = w;                 w += (size_t)NDRUG * HID;
  p.xi1 = w;                 w += (size_t)NDIS * HID;
  p.xd2 = w;                 w += (size_t)NDRUG * HID;
  p.xi2 = w;                 w += (size_t)NDIS * HID;
  p.hsb = w;                 w += (size_t)NDIS * HID;
  p.alphaB = w;              w += (size_t)2 * NREL * NDIS;
  p.wv = w;                  w += 14 * 256;
  p.amax = (unsigned*)w;     w += (size_t)NREL * NDIS;
  p.denom = w;               w += (size_t)NREL * NDIS;
  p.alpha_e = w;             w += (size_t)NREL * NE;
  p.total_bytes = (size_t)((char*)w - (char*)d_ws);
  return p;
}

static void run_layer(const float* XD, const float* XI, int K,
                      const float* Wsrc, const float* Wdst,
                      const float* as_, const float* ad_, const float* bias,
                      float* outD, float* outI,
                      const WsPlan& p, const RelIdx& ri,
                      const int* const* esrc, const int* const* edst,
                      hipStream_t stream)
{
  // 1. w vectors (14 GEMVs of the weight matrices)
  wvec_kernel<<<14, 256, 0, stream>>>(Wsrc, as_, Wdst, ad_, p.wv, K);

  // 2. alpha vectors via batched GEMV on node features
  AlphaJobs jd = {};
  jd.wslot[0] = 0; jd.outOff[0] = 0 * NDIS;        // src r0
  jd.wslot[1] = 2; jd.outOff[1] = 2 * NDIS;        // src r2
  jd.wslot[2] = 6; jd.outOff[2] = 6 * NDIS;        // src r6
  jd.wslot[3] = 7 + 1; jd.outOff[3] = (7 + 1) * NDIS;  // dst r1
  jd.wslot[4] = 7 + 3; jd.outOff[4] = (7 + 3) * NDIS;  // dst r3
  jd.wslot[5] = 7 + 6; jd.outOff[5] = (7 + 6) * NDIS;  // dst r6
  AlphaJobs ji = {};
  ji.wslot[0] = 1; ji.outOff[0] = 1 * NDIS;
  ji.wslot[1] = 3; ji.outOff[1] = 3 * NDIS;
  ji.wslot[2] = 4; ji.outOff[2] = 4 * NDIS;
  ji.wslot[3] = 5; ji.outOff[3] = 5 * NDIS;
  ji.wslot[4] = 7 + 0; ji.outOff[4] = (7 + 0) * NDIS;
  ji.wslot[5] = 7 + 2; ji.outOff[5] = (7 + 2) * NDIS;
  ji.wslot[6] = 7 + 4; ji.outOff[6] = (7 + 4) * NDIS;
  ji.wslot[7] = 7 + 5; ji.outOff[7] = (7 + 5) * NDIS;

  int gbD = (NDRUG + 255) / 256, gbI = (NDIS + 255) / 256;
  if (K == 256) {
    alpha_batch<6, 256><<<gbD, 256, 0, stream>>>(XD, NDRUG, p.wv, p.alphaB, jd);
    alpha_batch<8, 256><<<gbI, 256, 0, stream>>>(XI, NDIS, p.wv, p.alphaB, ji);
  } else {
    alpha_batch<6, 128><<<gbD, 256, 0, stream>>>(XD, NDRUG, p.wv, p.alphaB, jd);
    alpha_batch<8, 128><<<gbI, 256, 0, stream>>>(XI, NDIS, p.wv, p.alphaB, ji);
  }

  // 3. init segment-max / denom; init outputs with summed biases
  init_md<<<(NREL * NDIS + 255) / 256, 256, 0, stream>>>(p.amax, p.denom);
  int maskD = 0, maskI = 0;
  for (int r = 0; r < NREL; ++r) { if (DSTh[r] == 0) maskD |= 1 << r; else maskI |= 1 << r; }
  init_out<<<2048, 256, 0, stream>>>(outD, NDRUG, bias, maskD);
  init_out<<<2048, 256, 0, stream>>>(outI, NDIS, bias, maskI);

  // 4. edge softmax (batched over relations)
  dim3 g1((NE + 255) / 256, NREL);
  edge_pass1<<<g1, 256, 0, stream>>>(ri, p.alphaB, p.amax, p.alpha_e);
  edge_pass2<<<g1, 256, 0, stream>>>(ri, p.amax, p.alpha_e, p.denom);

  // 5. per relation: hs GEMM + weighted scatter
  for (int r = 0; r < NREL; ++r) {
    const float* Xs = SRCh[r] == 0 ? XD : XI;
    int Ns = SRCh[r] == 0 ? NDRUG : NDIS;
    if (K == 256)
      gemm128<256, false, false><<<(Ns + 63) / 64, 256, 0, stream>>>(
          Xs, Wsrc + (size_t)r * 256 * HID, nullptr, p.hsb, Ns);
    else
      gemm128<128, false, false><<<(Ns + 63) / 64, 256, 0, stream>>>(
          Xs, Wsrc + (size_t)r * 128 * HID, nullptr, p.hsb, Ns);
    float* outp = DSTh[r] == 0 ? outD : outI;
    edge_pass3<<<(NE * 32 + 255) / 256, 256, 0, stream>>>(
        esrc[r], edst[r], p.alpha_e + (size_t)r * NE, p.denom + (size_t)r * NDIS,
        p.hsb, outp);
  }
}

extern "C" void kernel_launch(void* const* d_in, const int* in_sizes, int n_in,
                              void* d_out, int out_size, void* d_ws, size_t ws_size,
                              hipStream_t stream) {
  const float* x_drug = (const float*)d_in[0];
  const float* x_dis  = (const float*)d_in[1];
  const int* esrc[NREL]; const int* edst[NREL];
  for (int r = 0; r < NREL; ++r) {
    const int* e = (const int*)d_in[2 + r];
    esrc[r] = e; edst[r] = e + NE;
  }
  const float* W1s = (const float*)d_in[9];
  const float* W1d = (const float*)d_in[10];
  const float* a1s = (const float*)d_in[11];
  const float* a1d = (const float*)d_in[12];
  const float* b1  = (const float*)d_in[13];
  const float* W2s = (const float*)d_in[14];
  const float* W2d = (const float*)d_in[15];
  const float* a2s = (const float*)d_in[16];
  const float* a2d = (const float*)d_in[17];
  const float* b2  = (const float*)d_in[18];
  const float* Wdr = (const float*)d_in[19];
  const float* bdr = (const float*)d_in[20];
  const float* Wdi = (const float*)d_in[21];
  const float* bdi = (const float*)d_in[22];

  WsPlan p = plan_ws(d_ws);
  if (p.total_bytes > ws_size) return;  // insufficient workspace — fail visibly

  RelIdx ri;
  for (int r = 0; r < NREL; ++r) { ri.src[r] = esrc[r]; ri.dst[r] = edst[r]; }

  // Layer 1 (K = 256)
  run_layer(x_drug, x_dis, 256, W1s, W1d, a1s, a1d, b1, p.xd1, p.xi1,
            p, ri, esrc, edst, stream);
  relu_k<<<2048, 256, 0, stream>>>(p.xd1, NDRUG * HID / 4);
  relu_k<<<2048, 256, 0, stream>>>(p.xi1, NDIS * HID / 4);

  // Layer 2 (K = 128)
  run_layer(p.xd1, p.xi1, 128, W2s, W2d, a2s, a2d, b2, p.xd2, p.xi2,
            p, ri, esrc, edst, stream);

  // Final linear + relu into d_out
  float* out = (float*)d_out;
  gemm128<128, true, true><<<(NDRUG + 63) / 64, 256, 0, stream>>>(
      p.xd2, Wdr, bdr, out, NDRUG);
  gemm128<128, true, true><<<(NDIS + 63) / 64, 256, 0, stream>>>(
      p.xi2, Wdi, bdi, out + (size_t)NDRUG * HID, NDIS);
}

// Round 2
// 1304.258 us; speedup vs baseline: 3.3851x; 3.3851x over previous
//
#include <hip/hip_runtime.h>
#include <stdint.h>

#define NDRUG 20000
#define NDIS  40000
#define DIN   256
#define HID   128
#define NE    150000
#define NREL  7
#define RPSTR (NDIS + 1)   // rowptr stride per relation

// ---------- GEMM: C[M,128] = A[M,K] @ W[K,128] (+bias, +relu) ----------
template<int K, bool BIAS, bool RELU>
__global__ __launch_bounds__(256) void gemm128(const float* __restrict__ A,
                                               const float* __restrict__ W,
                                               const float* __restrict__ bias,
                                               float* __restrict__ C, int M)
{
  __shared__ float As[32][65];    // A tile transposed [k][row], +1 pad
  __shared__ float Bs[32][128];   // W tile [k][col]
  const int tid = threadIdx.x;
  const int m0  = blockIdx.x * 64;
  const int tr  = tid >> 5;   // 0..7 row-group
  const int tc  = tid & 31;   // 0..31 col-group
  float acc[8][4] = {};

  for (int k0 = 0; k0 < K; k0 += 32) {
    #pragma unroll
    for (int i = 0; i < 2; ++i) {
      int f = tid + 256 * i;
      int row = f >> 3, kk = (f & 7) << 2;
      float4 v = make_float4(0.f, 0.f, 0.f, 0.f);
      int gr = m0 + row;
      if (gr < M) v = *reinterpret_cast<const float4*>(A + (size_t)gr * K + k0 + kk);
      As[kk + 0][row] = v.x; As[kk + 1][row] = v.y;
      As[kk + 2][row] = v.z; As[kk + 3][row] = v.w;
    }
    #pragma unroll
    for (int i = 0; i < 4; ++i) {
      int f = tid + 256 * i;
      int wr = f >> 5, wc = (f & 31) << 2;
      *reinterpret_cast<float4*>(&Bs[wr][wc]) =
          *reinterpret_cast<const float4*>(W + (size_t)(k0 + wr) * HID + wc);
    }
    __syncthreads();
    #pragma unroll
    for (int k = 0; k < 32; ++k) {
      float a[8];
      #pragma unroll
      for (int i = 0; i < 8; ++i) a[i] = As[k][tr * 8 + i];
      const float4 b4 = *reinterpret_cast<const float4*>(&Bs[k][tc * 4]);
      const float bb[4] = {b4.x, b4.y, b4.z, b4.w};
      #pragma unroll
      for (int i = 0; i < 8; ++i)
        #pragma unroll
        for (int j = 0; j < 4; ++j)
          acc[i][j] += a[i] * bb[j];
    }
    __syncthreads();
  }

  float4 bv = make_float4(0.f, 0.f, 0.f, 0.f);
  if (BIAS) bv = *reinterpret_cast<const float4*>(bias + tc * 4);
  #pragma unroll
  for (int i = 0; i < 8; ++i) {
    int gr = m0 + tr * 8 + i;
    if (gr >= M) continue;
    float4 v = make_float4(acc[i][0], acc[i][1], acc[i][2], acc[i][3]);
    if (BIAS) { v.x += bv.x; v.y += bv.y; v.z += bv.z; v.w += bv.w; }
    if (RELU) {
      v.x = fmaxf(v.x, 0.f); v.y = fmaxf(v.y, 0.f);
      v.z = fmaxf(v.z, 0.f); v.w = fmaxf(v.w, 0.f);
    }
    *reinterpret_cast<float4*>(C + (size_t)gr * HID + tc * 4) = v;
  }
}

// ---------- wvec: w[slot][k] = sum_j W[r][k][j] * a[r][j] ----------
__global__ void wvec_kernel(const float* __restrict__ Wsrc, const float* __restrict__ as_,
                            const float* __restrict__ Wdst, const float* __restrict__ ad_,
                            float* __restrict__ wv, int K)
{
  int slot = blockIdx.x;   // 0..13
  int r = slot % NREL;
  const float* W = (slot < NREL ? Wsrc : Wdst) + (size_t)r * K * HID;
  const float* a = (slot < NREL ? as_ : ad_) + r * HID;
  __shared__ float sa[HID];
  if (threadIdx.x < HID) sa[threadIdx.x] = a[threadIdx.x];
  __syncthreads();
  for (int k = threadIdx.x; k < K; k += blockDim.x) {
    const float* wr = W + (size_t)k * HID;
    float s = 0.f;
    #pragma unroll 4
    for (int j = 0; j < HID; ++j) s += wr[j] * sa[j];
    wv[slot * 256 + k] = s;
  }
}

// ---------- batched GEMV: alpha[v][i] = dot(X[i], wv[slot_v]) ----------
struct AlphaJobs { int wslot[8]; int outOff[8]; };

template<int NV, int K>
__global__ __launch_bounds__(256) void alpha_batch(const float* __restrict__ X, int N,
                                                   const float* __restrict__ wv,
                                                   float* __restrict__ outBase, AlphaJobs jobs)
{
  int i = blockIdx.x * blockDim.x + threadIdx.x;
  if (i >= N) return;
  float acc[NV];
  #pragma unroll
  for (int v = 0; v < NV; ++v) acc[v] = 0.f;
  const float* xp = X + (size_t)i * K;
  #pragma unroll 4
  for (int k = 0; k < K; k += 4) {
    float4 x = *reinterpret_cast<const float4*>(xp + k);
    #pragma unroll
    for (int v = 0; v < NV; ++v) {
      const float4 w = *reinterpret_cast<const float4*>(wv + jobs.wslot[v] * 256 + k);
      acc[v] += x.x * w.x + x.y * w.y + x.z * w.z + x.w * w.w;
    }
  }
  #pragma unroll
  for (int v = 0; v < NV; ++v) outBase[jobs.outOff[v] + i] = acc[v];
}

// ---------- CSR build ----------
struct RelIdx { const int* src[NREL]; const int* dst[NREL]; };
struct NdArr  { int nd[NREL]; };

__global__ void zero_ints(int* __restrict__ p, int n) {
  int i = blockIdx.x * blockDim.x + threadIdx.x;
  if (i < n) p[i] = 0;
}

__global__ void hist_k(RelIdx ri, int* __restrict__ counts) {
  int e = blockIdx.x * blockDim.x + threadIdx.x;
  int r = blockIdx.y;
  if (e >= NE) return;
  atomicAdd(&counts[r * RPSTR + ri.dst[r][e]], 1);
}

// one block (1024 thr) per relation: exclusive scan counts -> rowptr
__global__ __launch_bounds__(1024) void scan_k(const int* __restrict__ counts,
                                               int* __restrict__ rowptr, NdArr nds)
{
  int r = blockIdx.x;
  int Nd = nds.nd[r];
  int base = r * RPSTR;
  int t = threadIdx.x;
  int CH = (Nd + 1023) / 1024;
  int start = t * CH;
  int s = 0;
  for (int i = 0; i < CH; ++i) {
    int idx = start + i;
    if (idx < Nd) s += counts[base + idx];
  }
  __shared__ int ps[1024];
  ps[t] = s; __syncthreads();
  for (int off = 1; off < 1024; off <<= 1) {
    int v = (t >= off) ? ps[t - off] : 0;
    __syncthreads();
    ps[t] += v;
    __syncthreads();
  }
  int run = ps[t] - s;   // exclusive
  for (int i = 0; i < CH; ++i) {
    int idx = start + i;
    if (idx < Nd) { rowptr[base + idx] = run; run += counts[base + idx]; }
  }
  if (t == 0) rowptr[base + Nd] = ps[1023];
}

__global__ void copy_ints(const int* __restrict__ a, int* __restrict__ b, int n) {
  int i = blockIdx.x * blockDim.x + threadIdx.x;
  if (i < n) b[i] = a[i];
}

__global__ void fill_k(RelIdx ri, int* __restrict__ cursor, int* __restrict__ colsrc) {
  int e = blockIdx.x * blockDim.x + threadIdx.x;
  int r = blockIdx.y;
  if (e >= NE) return;
  int d = ri.dst[r][e];
  int pos = atomicAdd(&cursor[r * RPSTR + d], 1);
  colsrc[r * NE + pos] = ri.src[r][e];
}

// ---------- fused per-dst softmax + gather-aggregate ----------
// one 128-thread block per dst node; out[d] += sum_e coef_e * hs[src_e]
__global__ __launch_bounds__(128) void aggregate(
    const int* __restrict__ rowptr, const int* __restrict__ colsrc,
    const float* __restrict__ alpha_s, const float* __restrict__ alpha_d,
    const float* __restrict__ hs, float* __restrict__ out)
{
  int d = blockIdx.x;
  int beg = rowptr[d], end = rowptr[d + 1];
  if (beg == end) return;
  const float ad = alpha_d[d];
  const int t = threadIdx.x;
  __shared__ float sc[128];
  __shared__ int   ss[128];
  __shared__ float red[128];

  // pass 1: segment max
  float m = -1e30f;
  for (int i = beg + t; i < end; i += 128) {
    float a = alpha_s[colsrc[i]] + ad;
    a = a > 0.f ? a : 0.2f * a;
    m = fmaxf(m, a);
  }
  red[t] = m; __syncthreads();
  #pragma unroll
  for (int off = 64; off; off >>= 1) {
    if (t < off) red[t] = fmaxf(red[t], red[t + off]);
    __syncthreads();
  }
  m = red[0];

  // pass 2: exp, denom partial, weighted accumulate (thread t = column t)
  float acc = 0.f, dsum = 0.f;
  for (int c0 = beg; c0 < end; c0 += 128) {
    int n = min(128, end - c0);
    __syncthreads();          // protect red[0] read + sc/ss reuse
    if (t < n) {
      int s = colsrc[c0 + t];
      float a = alpha_s[s] + ad;
      a = a > 0.f ? a : 0.2f * a;
      float ex = __expf(a - m);
      sc[t] = ex; ss[t] = s;
      dsum += ex;
    }
    __syncthreads();
    for (int i = 0; i < n; ++i)
      acc += sc[i] * hs[(size_t)ss[i] * HID + t];
  }
  __syncthreads();
  red[t] = dsum; __syncthreads();
  #pragma unroll
  for (int off = 64; off; off >>= 1) {
    if (t < off) red[t] += red[t + off];
    __syncthreads();
  }
  float denom = red[0];
  out[(size_t)d * HID + t] += acc / (denom + 1e-16f);
}

// ---------- misc ----------
__global__ void init_out(float* __restrict__ out, int N, const float* __restrict__ b, int mask) {
  __shared__ float sb[HID];
  if (threadIdx.x < HID) {
    float s = 0.f;
    for (int r = 0; r < NREL; ++r)
      if (mask & (1 << r)) s += b[r * HID + threadIdx.x];
    sb[threadIdx.x] = s;
  }
  __syncthreads();
  int total = N * (HID / 4);
  for (int idx = blockIdx.x * blockDim.x + threadIdx.x; idx < total;
       idx += gridDim.x * blockDim.x) {
    int j = (idx & 31) << 2;
    float4 v = make_float4(sb[j], sb[j + 1], sb[j + 2], sb[j + 3]);
    *reinterpret_cast<float4*>(out + (size_t)idx * 4) = v;
  }
}

__global__ void relu_k(float* __restrict__ x, int n4) {
  for (int i = blockIdx.x * blockDim.x + threadIdx.x; i < n4; i += gridDim.x * blockDim.x) {
    float4 v = *reinterpret_cast<float4*>(x + (size_t)i * 4);
    v.x = fmaxf(v.x, 0.f); v.y = fmaxf(v.y, 0.f);
    v.z = fmaxf(v.z, 0.f); v.w = fmaxf(v.w, 0.f);
    *reinterpret_cast<float4*>(x + (size_t)i * 4) = v;
  }
}

// ---------- host ----------
static const int SRCh[NREL] = {0, 1, 0, 1, 1, 1, 0};
static const int DSTh[NREL] = {1, 0, 1, 0, 1, 1, 0};

struct WsPlan {
  float* xd1; float* xi1; float* xd2; float* xi2;
  float* hsb; float* alphaB; float* wv;
  int* counts; int* rowptr; int* cursor; int* colsrc;
  size_t total_bytes;
};

static WsPlan plan_ws(void* d_ws) {
  WsPlan p;
  float* w = (float*)d_ws;
  p.xd1 = w;               w += (size_t)NDRUG * HID;
  p.xi1 = w;               w += (size_t)NDIS * HID;
  p.xd2 = w;               w += (size_t)NDRUG * HID;
  p.xi2 = w;               w += (size_t)NDIS * HID;
  p.hsb = w;               w += (size_t)NDIS * HID;
  p.alphaB = w;            w += (size_t)2 * NREL * NDIS;
  p.wv = w;                w += 14 * 256;
  int* q = (int*)w;
  p.counts = q;            q += NREL * RPSTR;
  p.rowptr = q;            q += NREL * RPSTR;
  p.cursor = q;            q += NREL * RPSTR;
  p.colsrc = q;            q += NREL * NE;
  p.total_bytes = (size_t)((char*)q - (char*)d_ws);
  return p;
}

static void run_layer(const float* XD, const float* XI, int K,
                      const float* Wsrc, const float* Wdst,
                      const float* as_, const float* ad_, const float* bias,
                      float* outD, float* outI,
                      const WsPlan& p, hipStream_t stream)
{
  wvec_kernel<<<14, 256, 0, stream>>>(Wsrc, as_, Wdst, ad_, p.wv, K);

  AlphaJobs jd = {};
  jd.wslot[0] = 0;     jd.outOff[0] = 0 * NDIS;
  jd.wslot[1] = 2;     jd.outOff[1] = 2 * NDIS;
  jd.wslot[2] = 6;     jd.outOff[2] = 6 * NDIS;
  jd.wslot[3] = 7 + 1; jd.outOff[3] = (7 + 1) * NDIS;
  jd.wslot[4] = 7 + 3; jd.outOff[4] = (7 + 3) * NDIS;
  jd.wslot[5] = 7 + 6; jd.outOff[5] = (7 + 6) * NDIS;
  AlphaJobs ji = {};
  ji.wslot[0] = 1;     ji.outOff[0] = 1 * NDIS;
  ji.wslot[1] = 3;     ji.outOff[1] = 3 * NDIS;
  ji.wslot[2] = 4;     ji.outOff[2] = 4 * NDIS;
  ji.wslot[3] = 5;     ji.outOff[3] = 5 * NDIS;
  ji.wslot[4] = 7 + 0; ji.outOff[4] = (7 + 0) * NDIS;
  ji.wslot[5] = 7 + 2; ji.outOff[5] = (7 + 2) * NDIS;
  ji.wslot[6] = 7 + 4; ji.outOff[6] = (7 + 4) * NDIS;
  ji.wslot[7] = 7 + 5; ji.outOff[7] = (7 + 5) * NDIS;

  int gbD = (NDRUG + 255) / 256, gbI = (NDIS + 255) / 256;
  if (K == 256) {
    alpha_batch<6, 256><<<gbD, 256, 0, stream>>>(XD, NDRUG, p.wv, p.alphaB, jd);
    alpha_batch<8, 256><<<gbI, 256, 0, stream>>>(XI, NDIS, p.wv, p.alphaB, ji);
  } else {
    alpha_batch<6, 128><<<gbD, 256, 0, stream>>>(XD, NDRUG, p.wv, p.alphaB, jd);
    alpha_batch<8, 128><<<gbI, 256, 0, stream>>>(XI, NDIS, p.wv, p.alphaB, ji);
  }

  int maskD = 0, maskI = 0;
  for (int r = 0; r < NREL; ++r) { if (DSTh[r] == 0) maskD |= 1 << r; else maskI |= 1 << r; }
  init_out<<<1024, 256, 0, stream>>>(outD, NDRUG, bias, maskD);
  init_out<<<1024, 256, 0, stream>>>(outI, NDIS, bias, maskI);

  for (int r = 0; r < NREL; ++r) {
    const float* Xs = SRCh[r] == 0 ? XD : XI;
    int Ns = SRCh[r] == 0 ? NDRUG : NDIS;
    int Nd = DSTh[r] == 0 ? NDRUG : NDIS;
    if (K == 256)
      gemm128<256, false, false><<<(Ns + 63) / 64, 256, 0, stream>>>(
          Xs, Wsrc + (size_t)r * 256 * HID, nullptr, p.hsb, Ns);
    else
      gemm128<128, false, false><<<(Ns + 63) / 64, 256, 0, stream>>>(
          Xs, Wsrc + (size_t)r * 128 * HID, nullptr, p.hsb, Ns);
    float* outp = DSTh[r] == 0 ? outD : outI;
    aggregate<<<Nd, 128, 0, stream>>>(
        p.rowptr + r * RPSTR, p.colsrc + (size_t)r * NE,
        p.alphaB + (size_t)r * NDIS, p.alphaB + (size_t)(NREL + r) * NDIS,
        p.hsb, outp);
  }
}

extern "C" void kernel_launch(void* const* d_in, const int* in_sizes, int n_in,
                              void* d_out, int out_size, void* d_ws, size_t ws_size,
                              hipStream_t stream) {
  const float* x_drug = (const float*)d_in[0];
  const float* x_dis  = (const float*)d_in[1];
  RelIdx ri;
  for (int r = 0; r < NREL; ++r) {
    const int* e = (const int*)d_in[2 + r];
    ri.src[r] = e; ri.dst[r] = e + NE;
  }
  const float* W1s = (const float*)d_in[9];
  const float* W1d = (const float*)d_in[10];
  const float* a1s = (const float*)d_in[11];
  const float* a1d = (const float*)d_in[12];
  const float* b1  = (const float*)d_in[13];
  const float* W2s = (const float*)d_in[14];
  const float* W2d = (const float*)d_in[15];
  const float* a2s = (const float*)d_in[16];
  const float* a2d = (const float*)d_in[17];
  const float* b2  = (const float*)d_in[18];
  const float* Wdr = (const float*)d_in[19];
  const float* bdr = (const float*)d_in[20];
  const float* Wdi = (const float*)d_in[21];
  const float* bdi = (const float*)d_in[22];

  WsPlan p = plan_ws(d_ws);
  if (p.total_bytes > ws_size) return;

  // ---- CSR build (once; reused by both layers) ----
  NdArr nds;
  for (int r = 0; r < NREL; ++r) nds.nd[r] = DSTh[r] == 0 ? NDRUG : NDIS;
  int ncnt = NREL * RPSTR;
  zero_ints<<<(ncnt + 255) / 256, 256, 0, stream>>>(p.counts, ncnt);
  dim3 ge((NE + 255) / 256, NREL);
  hist_k<<<ge, 256, 0, stream>>>(ri, p.counts);
  scan_k<<<NREL, 1024, 0, stream>>>(p.counts, p.rowptr, nds);
  copy_ints<<<(ncnt + 255) / 256, 256, 0, stream>>>(p.rowptr, p.cursor, ncnt);
  fill_k<<<ge, 256, 0, stream>>>(ri, p.cursor, p.colsrc);

  // Layer 1 (K = 256)
  run_layer(x_drug, x_dis, 256, W1s, W1d, a1s, a1d, b1, p.xd1, p.xi1, p, stream);
  relu_k<<<1024, 256, 0, stream>>>(p.xd1, NDRUG * HID / 4);
  relu_k<<<1024, 256, 0, stream>>>(p.xi1, NDIS * HID / 4);

  // Layer 2 (K = 128)
  run_layer(p.xd1, p.xi1, 128, W2s, W2d, a2s, a2d, b2, p.xd2, p.xi2, p, stream);

  // Final linear + relu into d_out
  float* out = (float*)d_out;
  gemm128<128, true, true><<<(NDRUG + 63) / 64, 256, 0, stream>>>(
      p.xd2, Wdr, bdr, out, NDRUG);
  gemm128<128, true, true><<<(NDIS + 63) / 64, 256, 0, stream>>>(
      p.xi2, Wdi, bdi, out + (size_t)NDRUG * HID, NDIS);
}

// Round 3
// 550.015 us; speedup vs baseline: 8.0272x; 2.3713x over previous
//
#include <hip/hip_runtime.h>
#include <stdint.h>

#define NDRUG 20000
#define NDIS  40000
#define HID   128
#define NE    150000
#define NREL  7
#define RPSTR (NDIS + 1)
#define NS_TOT (NREL * RPSTR)

typedef unsigned short ushort_t;
typedef __attribute__((ext_vector_type(8))) short bf16x8;
typedef __attribute__((ext_vector_type(4))) float f32x4;

__device__ __forceinline__ ushort_t f2bf(float f) {
  unsigned u = __float_as_uint(f);
  u += 0x7FFFu + ((u >> 16) & 1u);          // RNE
  return (ushort_t)(u >> 16);
}
__device__ __forceinline__ float bf2f(ushort_t h) {
  return __uint_as_float(((unsigned)h) << 16);
}

// ================= bf16 MFMA GEMM: C[M,N] = A[M,K] @ BT[N,K]^T =================
// A,BT bf16 row-major. N multiple of 128, K multiple of 32. 128x128 tile, 4 waves.
template<bool BIAS, bool RELU, bool BF16OUT>
__global__ __launch_bounds__(256) void mfma_gemm(
    const ushort_t* __restrict__ A, const ushort_t* __restrict__ BT,
    const float* __restrict__ bias, void* __restrict__ Cout, int M, int N, int K)
{
  __shared__ ushort_t As[128 * 40];   // 80B rows (32 bf16 + 8 pad)
  __shared__ ushort_t Bs[128 * 40];
  const int tid = threadIdx.x;
  const int m0 = blockIdx.x * 128;
  const int n0 = blockIdx.y * 128;
  const int wave = tid >> 6, lane = tid & 63;
  const int wm = wave & 1, wn = wave >> 1;
  const int l15 = lane & 15, lk = lane >> 4;

  f32x4 acc[4][4] = {};

  for (int k0 = 0; k0 < K; k0 += 32) {
    __syncthreads();
    #pragma unroll
    for (int i = 0; i < 2; ++i) {
      int c = tid + 256 * i;               // 0..511
      int row = c >> 2, kc = (c & 3) << 3; // 8 bf16 chunks
      uint4 v = make_uint4(0u, 0u, 0u, 0u);
      int gr = m0 + row;
      if (gr < M) v = *reinterpret_cast<const uint4*>(A + (size_t)gr * K + k0 + kc);
      *reinterpret_cast<uint4*>(&As[row * 40 + kc]) = v;
      uint4 w = *reinterpret_cast<const uint4*>(BT + (size_t)(n0 + row) * K + k0 + kc);
      *reinterpret_cast<uint4*>(&Bs[row * 40 + kc]) = w;
    }
    __syncthreads();
    bf16x8 af[4], bfg[4];
    #pragma unroll
    for (int m = 0; m < 4; ++m)
      af[m] = *reinterpret_cast<const bf16x8*>(&As[(wm * 64 + m * 16 + l15) * 40 + lk * 8]);
    #pragma unroll
    for (int n = 0; n < 4; ++n)
      bfg[n] = *reinterpret_cast<const bf16x8*>(&Bs[(wn * 64 + n * 16 + l15) * 40 + lk * 8]);
    #pragma unroll
    for (int m = 0; m < 4; ++m)
      #pragma unroll
      for (int n = 0; n < 4; ++n)
        acc[m][n] = __builtin_amdgcn_mfma_f32_16x16x32_bf16(af[m], bfg[n], acc[m][n], 0, 0, 0);
  }

  #pragma unroll
  for (int m = 0; m < 4; ++m) {
    int rbase = m0 + wm * 64 + m * 16 + lk * 4;
    #pragma unroll
    for (int n = 0; n < 4; ++n) {
      int col = n0 + wn * 64 + n * 16 + l15;
      float bv = 0.f;
      if (BIAS) bv = bias[col];
      #pragma unroll
      for (int j = 0; j < 4; ++j) {
        int row = rbase + j;
        if (row >= M) continue;
        float v = acc[m][n][j] + bv;
        if (RELU) v = fmaxf(v, 0.f);
        if (BF16OUT) ((ushort_t*)Cout)[(size_t)row * N + col] = f2bf(v);
        else         ((float*)Cout)[(size_t)row * N + col] = v;
      }
    }
  }
}

// ================= weight prep =================
// out[c][k] = bf16(W[rel(c)][k][c&127]) ; rel(c) from int4 by 128-col group
__global__ void build_wcatT(const float* __restrict__ W, ushort_t* __restrict__ out,
                            int K, int ncol, int4 rels)
{
  int id = blockIdx.x * 256 + threadIdx.x;
  int tot = K * ncol;
  if (id >= tot) return;
  int k = id / ncol, c = id - k * ncol;
  int rr = (&rels.x)[c >> 7];
  out[(size_t)c * K + k] = f2bf(W[((size_t)rr * K + k) * HID + (c & 127)]);
}

// wv[slot][k] = sum_j W[r][k][j] * a[r][j]   (slot<7: src, else dst)
__global__ __launch_bounds__(256) void wvec_kernel(
    const float* __restrict__ Wsrc, const float* __restrict__ as_,
    const float* __restrict__ Wdst, const float* __restrict__ ad_,
    float* __restrict__ wv, int K)
{
  int slot = blockIdx.x;
  int r = slot % NREL;
  const float* W = (slot < NREL ? Wsrc : Wdst) + (size_t)r * K * HID;
  const float* a = (slot < NREL ? as_ : ad_) + r * HID;
  int wave = threadIdx.x >> 6, lane = threadIdx.x & 63;
  int k = blockIdx.y * 4 + wave;
  if (k >= K) return;
  float s = W[(size_t)k * HID + lane] * a[lane]
          + W[(size_t)k * HID + 64 + lane] * a[64 + lane];
  #pragma unroll
  for (int off = 32; off; off >>= 1) s += __shfl_xor(s, off);
  if (lane == 0) wv[slot * 256 + k] = s;
}

// ================= f32 -> bf16 convert =================
__global__ void cvt_f32_bf16(const float* __restrict__ in, ushort_t* __restrict__ out, int n8) {
  int i = blockIdx.x * 256 + threadIdx.x;
  if (i >= n8) return;
  float4 a = reinterpret_cast<const float4*>(in)[2 * i];
  float4 b = reinterpret_cast<const float4*>(in)[2 * i + 1];
  ushort_t r[8] = {f2bf(a.x), f2bf(a.y), f2bf(a.z), f2bf(a.w),
                   f2bf(b.x), f2bf(b.y), f2bf(b.z), f2bf(b.w)};
  reinterpret_cast<uint4*>(out)[i] = *reinterpret_cast<uint4*>(r);
}

// ================= batched alpha GEMV (bf16 X) =================
struct AlphaJobs { int wslot[8]; int outOff[8]; };

template<int NV, int K>
__global__ __launch_bounds__(256) void alpha_batch(
    const ushort_t* __restrict__ X, int N, const float* __restrict__ wv,
    float* __restrict__ outBase, AlphaJobs jobs)
{
  int i = blockIdx.x * 256 + threadIdx.x;
  if (i >= N) return;
  float acc[NV];
  #pragma unroll
  for (int v = 0; v < NV; ++v) acc[v] = 0.f;
  const ushort_t* xp = X + (size_t)i * K;
  for (int k = 0; k < K; k += 8) {
    uint4 u = *reinterpret_cast<const uint4*>(xp + k);
    unsigned uu[4] = {u.x, u.y, u.z, u.w};
    float xf[8];
    #pragma unroll
    for (int q = 0; q < 4; ++q) {
      xf[2 * q]     = __uint_as_float(uu[q] << 16);
      xf[2 * q + 1] = __uint_as_float(uu[q] & 0xFFFF0000u);
    }
    #pragma unroll
    for (int v = 0; v < NV; ++v) {
      const float* wp = wv + jobs.wslot[v] * 256 + k;
      #pragma unroll
      for (int q = 0; q < 8; ++q) acc[v] += xf[q] * wp[q];
    }
  }
  #pragma unroll
  for (int v = 0; v < NV; ++v) outBase[jobs.outOff[v] + i] = acc[v];
}

// ================= CSR build =================
struct RelIdx { const int* src[NREL]; const int* dst[NREL]; };

__global__ void zero_ints(int* __restrict__ p, int n) {
  int i = blockIdx.x * 256 + threadIdx.x;
  if (i < n) p[i] = 0;
}
__global__ void hist_k(RelIdx ri, int* __restrict__ counts) {
  int e = blockIdx.x * 256 + threadIdx.x;
  int r = blockIdx.y;
  if (e >= NE) return;
  atomicAdd(&counts[r * RPSTR + ri.dst[r][e]], 1);
}
// 3-phase exclusive scan over counts[NS_TOT] -> rowptr (+cursor copy)
__global__ __launch_bounds__(256) void scan_blk(const int* __restrict__ in,
                                                int* __restrict__ partial,
                                                int* __restrict__ bsum, int n)
{
  __shared__ int ts[256];
  int t = threadIdx.x;
  int base = blockIdx.x * 1024 + t * 4;
  int v[4];
  #pragma unroll
  for (int i = 0; i < 4; ++i) v[i] = (base + i < n) ? in[base + i] : 0;
  int s = v[0] + v[1] + v[2] + v[3];
  ts[t] = s; __syncthreads();
  for (int off = 1; off < 256; off <<= 1) {
    int x = (t >= off) ? ts[t - off] : 0;
    __syncthreads();
    ts[t] += x;
    __syncthreads();
  }
  int run = ts[t] - s;
  #pragma unroll
  for (int i = 0; i < 4; ++i) {
    if (base + i < n) partial[base + i] = run;
    run += v[i];
  }
  if (t == 255) bsum[blockIdx.x] = ts[255];
}
__global__ __launch_bounds__(512) void scan_top(int* __restrict__ bsum, int nb) {
  __shared__ int ts[512];
  int t = threadIdx.x;
  int v = (t < nb) ? bsum[t] : 0;
  ts[t] = v; __syncthreads();
  for (int off = 1; off < 512; off <<= 1) {
    int x = (t >= off) ? ts[t - off] : 0;
    __syncthreads();
    ts[t] += x;
    __syncthreads();
  }
  if (t < nb) bsum[t] = ts[t] - v;
}
__global__ void scan_add(const int* __restrict__ partial, const int* __restrict__ bsum,
                         int* __restrict__ rowptr, int* __restrict__ cursor, int n)
{
  int i = blockIdx.x * 256 + threadIdx.x;
  if (i >= n) return;
  int v = partial[i] + bsum[i >> 10];
  rowptr[i] = v; cursor[i] = v;
}
__global__ void fill_k(RelIdx ri, int* __restrict__ cursor, int* __restrict__ colsrc) {
  int e = blockIdx.x * 256 + threadIdx.x;
  int r = blockIdx.y;
  if (e >= NE) return;
  int d = ri.dst[r][e];
  int pos = atomicAdd(&cursor[r * RPSTR + d], 1);
  colsrc[pos] = ri.src[r][e];
}

// ================= fused multi-relation aggregate (wave per dst node) =================
struct AggRel {
  int rel;          // relation id (for bias)
  int rowptr_off;   // r * RPSTR
  int as_off;       // r * NDIS
  int ad_off;       // (7+r) * NDIS
  const ushort_t* hs;
  int hst;          // hs row stride
  int hoff;         // hs col offset
};
template<int NR> struct AggP { AggRel rel[NR]; };

template<int NR, bool RELU>
__global__ __launch_bounds__(256) void aggregate_multi(
    AggP<NR> P, const int* __restrict__ rowptr, const int* __restrict__ colsrc,
    const float* __restrict__ alphaB, const float* __restrict__ bias,
    ushort_t* __restrict__ out, int Nd)
{
  int wave = threadIdx.x >> 6, lane = threadIdx.x & 63;
  int d = blockIdx.x * 4 + wave;
  if (d >= Nd) return;
  const int c0 = 2 * lane;
  float acc0 = 0.f, acc1 = 0.f;

  #pragma unroll
  for (int q = 0; q < NR; ++q) {
    const AggRel R = P.rel[q];
    acc0 += bias[R.rel * HID + c0];
    acc1 += bias[R.rel * HID + c0 + 1];
    int beg = rowptr[R.rowptr_off + d];
    int end = rowptr[R.rowptr_off + d + 1];
    int deg = end - beg;
    if (deg == 0) continue;
    float ad = alphaB[R.ad_off + d];
    float p0 = 0.f, p1 = 0.f, dsum = 0.f;

    if (deg <= 64) {
      float a = -1e30f; int s = 0;
      if (lane < deg) {
        s = colsrc[beg + lane];
        float t = alphaB[R.as_off + s] + ad;
        a = t > 0.f ? t : 0.2f * t;
      }
      float m = a;
      #pragma unroll
      for (int off = 32; off; off >>= 1) m = fmaxf(m, __shfl_xor(m, off));
      float ex = (lane < deg) ? __expf(a - m) : 0.f;
      dsum = ex;
      for (int i = 0; i < deg; ++i) {
        float ce = __shfl(ex, i);
        int si = __shfl(s, i);
        const ushort_t* hp = R.hs + (size_t)si * R.hst + R.hoff + c0;
        ushort2 hv = *reinterpret_cast<const ushort2*>(hp);
        p0 += ce * bf2f(hv.x);
        p1 += ce * bf2f(hv.y);
      }
    } else {
      float m = -1e30f;
      for (int c = beg + lane; c < end; c += 64) {
        float t = alphaB[R.as_off + colsrc[c]] + ad;
        t = t > 0.f ? t : 0.2f * t;
        m = fmaxf(m, t);
      }
      #pragma unroll
      for (int off = 32; off; off >>= 1) m = fmaxf(m, __shfl_xor(m, off));
      for (int cb = beg; cb < end; cb += 64) {
        int n = min(64, end - cb);
        float ex = 0.f; int s = 0;
        if (lane < n) {
          s = colsrc[cb + lane];
          float t = alphaB[R.as_off + s] + ad;
          t = t > 0.f ? t : 0.2f * t;
          ex = __expf(t - m);
        }
        dsum += ex;
        for (int i = 0; i < n; ++i) {
          float ce = __shfl(ex, i);
          int si = __shfl(s, i);
          const ushort_t* hp = R.hs + (size_t)si * R.hst + R.hoff + c0;
          ushort2 hv = *reinterpret_cast<const ushort2*>(hp);
          p0 += ce * bf2f(hv.x);
          p1 += ce * bf2f(hv.y);
        }
      }
    }
    #pragma unroll
    for (int off = 32; off; off >>= 1) dsum += __shfl_xor(dsum, off);
    float inv = 1.f / (dsum + 1e-16f);
    acc0 += p0 * inv;
    acc1 += p1 * inv;
  }
  if (RELU) { acc0 = fmaxf(acc0, 0.f); acc1 = fmaxf(acc1, 0.f); }
  ushort2 o; o.x = f2bf(acc0); o.y = f2bf(acc1);
  *reinterpret_cast<ushort2*>(out + (size_t)d * HID + c0) = o;
}

// ================= host =================
static const int SRCh[NREL] = {0, 1, 0, 1, 1, 1, 0};
static const int DSTh[NREL] = {1, 0, 1, 0, 1, 1, 0};

struct WsPlan {
  ushort_t *xdb1, *xib1, *xd1b, *xi1b, *xd2b, *xi2b;
  ushort_t *hs_d, *hs_i, *wcatT_d, *wcatT_i, *wfinT_d, *wfinT_i;
  float *alphaB, *wv;
  int *counts, *rowptr, *cursor, *colsrc, *bsum;
  size_t total_bytes;
};

static WsPlan plan_ws(void* d_ws) {
  WsPlan p;
  ushort_t* s = (ushort_t*)d_ws;
  p.xdb1 = s;     s += (size_t)NDRUG * 256;
  p.xib1 = s;     s += (size_t)NDIS * 256;
  p.xd1b = s;     s += (size_t)NDRUG * HID;
  p.xi1b = s;     s += (size_t)NDIS * HID;
  p.hs_d = s;     s += (size_t)NDRUG * 384;
  p.hs_i = s;     s += (size_t)NDIS * 512;
  p.wcatT_d = s;  s += 384 * 256;
  p.wcatT_i = s;  s += 512 * 256;
  p.wfinT_d = s;  s += 128 * 128;
  p.wfinT_i = s;  s += 128 * 128;
  p.xd2b = p.xdb1;   // alias: xdb1 dead after L1 GEMM/alpha
  p.xi2b = p.xib1;
  float* f = (float*)s;
  p.alphaB = f;   f += (size_t)2 * NREL * NDIS;
  p.wv = f;       f += 14 * 256;
  int* q = (int*)f;
  p.counts = q;   q += NS_TOT;
  p.rowptr = q;   q += NS_TOT;
  p.cursor = q;   q += NS_TOT;
  p.colsrc = q;   q += NREL * NE;
  p.bsum = q;     q += 512;
  p.total_bytes = (size_t)((char*)q - (char*)d_ws);
  return p;
}

static void run_layer(const ushort_t* XDb, const ushort_t* XIb, int K,
                      const float* Wsrc, const float* Wdst,
                      const float* as_, const float* ad_, const float* bias,
                      ushort_t* outDb, ushort_t* outIb, bool relu,
                      const WsPlan& p, hipStream_t stream)
{
  // weight prep
  int4 rd = make_int4(0, 2, 6, 0);
  int4 ri4 = make_int4(1, 3, 4, 5);
  build_wcatT<<<(K * 384 + 255) / 256, 256, 0, stream>>>(Wsrc, p.wcatT_d, K, 384, rd);
  build_wcatT<<<(K * 512 + 255) / 256, 256, 0, stream>>>(Wsrc, p.wcatT_i, K, 512, ri4);
  wvec_kernel<<<dim3(14, K / 4), 256, 0, stream>>>(Wsrc, as_, Wdst, ad_, p.wv, K);

  // alpha GEMVs
  AlphaJobs jd = {};
  jd.wslot[0] = 0;     jd.outOff[0] = 0 * NDIS;
  jd.wslot[1] = 2;     jd.outOff[1] = 2 * NDIS;
  jd.wslot[2] = 6;     jd.outOff[2] = 6 * NDIS;
  jd.wslot[3] = 7 + 1; jd.outOff[3] = (7 + 1) * NDIS;
  jd.wslot[4] = 7 + 3; jd.outOff[4] = (7 + 3) * NDIS;
  jd.wslot[5] = 7 + 6; jd.outOff[5] = (7 + 6) * NDIS;
  AlphaJobs ji = {};
  ji.wslot[0] = 1;     ji.outOff[0] = 1 * NDIS;
  ji.wslot[1] = 3;     ji.outOff[1] = 3 * NDIS;
  ji.wslot[2] = 4;     ji.outOff[2] = 4 * NDIS;
  ji.wslot[3] = 5;     ji.outOff[3] = 5 * NDIS;
  ji.wslot[4] = 7 + 0; ji.outOff[4] = (7 + 0) * NDIS;
  ji.wslot[5] = 7 + 2; ji.outOff[5] = (7 + 2) * NDIS;
  ji.wslot[6] = 7 + 4; ji.outOff[6] = (7 + 4) * NDIS;
  ji.wslot[7] = 7 + 5; ji.outOff[7] = (7 + 5) * NDIS;
  int gbD = (NDRUG + 255) / 256, gbI = (NDIS + 255) / 256;
  if (K == 256) {
    alpha_batch<6, 256><<<gbD, 256, 0, stream>>>(XDb, NDRUG, p.wv, p.alphaB, jd);
    alpha_batch<8, 256><<<gbI, 256, 0, stream>>>(XIb, NDIS, p.wv, p.alphaB, ji);
  } else {
    alpha_batch<6, 128><<<gbD, 256, 0, stream>>>(XDb, NDRUG, p.wv, p.alphaB, jd);
    alpha_batch<8, 128><<<gbI, 256, 0, stream>>>(XIb, NDIS, p.wv, p.alphaB, ji);
  }

  // hs GEMMs (bf16 out, no bias)
  mfma_gemm<false, false, true><<<dim3((NDRUG + 127) / 128, 3), 256, 0, stream>>>(
      XDb, p.wcatT_d, nullptr, p.hs_d, NDRUG, 384, K);
  mfma_gemm<false, false, true><<<dim3((NDIS + 127) / 128, 4), 256, 0, stream>>>(
      XIb, p.wcatT_i, nullptr, p.hs_i, NDIS, 512, K);

  // fused aggregates
  AggP<3> Pd;  // drug-dst rels {1,3,6}
  Pd.rel[0] = {1, 1 * RPSTR, 1 * NDIS, (7 + 1) * NDIS, p.hs_i, 512, 0};
  Pd.rel[1] = {3, 3 * RPSTR, 3 * NDIS, (7 + 3) * NDIS, p.hs_i, 512, 128};
  Pd.rel[2] = {6, 6 * RPSTR, 6 * NDIS, (7 + 6) * NDIS, p.hs_d, 384, 256};
  AggP<4> Pi;  // dis-dst rels {0,2,4,5}
  Pi.rel[0] = {0, 0 * RPSTR, 0 * NDIS, (7 + 0) * NDIS, p.hs_d, 384, 0};
  Pi.rel[1] = {2, 2 * RPSTR, 2 * NDIS, (7 + 2) * NDIS, p.hs_d, 384, 128};
  Pi.rel[2] = {4, 4 * RPSTR, 4 * NDIS, (7 + 4) * NDIS, p.hs_i, 512, 256};
  Pi.rel[3] = {5, 5 * RPSTR, 5 * NDIS, (7 + 5) * NDIS, p.hs_i, 512, 384};
  if (relu) {
    aggregate_multi<3, true><<<(NDRUG + 3) / 4, 256, 0, stream>>>(
        Pd, p.rowptr, p.colsrc, p.alphaB, bias, outDb, NDRUG);
    aggregate_multi<4, true><<<(NDIS + 3) / 4, 256, 0, stream>>>(
        Pi, p.rowptr, p.colsrc, p.alphaB, bias, outIb, NDIS);
  } else {
    aggregate_multi<3, false><<<(NDRUG + 3) / 4, 256, 0, stream>>>(
        Pd, p.rowptr, p.colsrc, p.alphaB, bias, outDb, NDRUG);
    aggregate_multi<4, false><<<(NDIS + 3) / 4, 256, 0, stream>>>(
        Pi, p.rowptr, p.colsrc, p.alphaB, bias, outIb, NDIS);
  }
}

extern "C" void kernel_launch(void* const* d_in, const int* in_sizes, int n_in,
                              void* d_out, int out_size, void* d_ws, size_t ws_size,
                              hipStream_t stream) {
  const float* x_drug = (const float*)d_in[0];
  const float* x_dis  = (const float*)d_in[1];
  RelIdx ri;
  for (int r = 0; r < NREL; ++r) {
    const int* e = (const int*)d_in[2 + r];
    ri.src[r] = e; ri.dst[r] = e + NE;
  }
  const float* W1s = (const float*)d_in[9];
  const float* W1d = (const float*)d_in[10];
  const float* a1s = (const float*)d_in[11];
  const float* a1d = (const float*)d_in[12];
  const float* b1  = (const float*)d_in[13];
  const float* W2s = (const float*)d_in[14];
  const float* W2d = (const float*)d_in[15];
  const float* a2s = (const float*)d_in[16];
  const float* a2d = (const float*)d_in[17];
  const float* b2  = (const float*)d_in[18];
  const float* Wdr = (const float*)d_in[19];
  const float* bdr = (const float*)d_in[20];
  const float* Wdi = (const float*)d_in[21];
  const float* bdi = (const float*)d_in[22];

  WsPlan p = plan_ws(d_ws);
  if (p.total_bytes > ws_size) return;

  // input conversion to bf16
  cvt_f32_bf16<<<(NDRUG * 256 / 8 + 255) / 256, 256, 0, stream>>>(x_drug, p.xdb1, NDRUG * 256 / 8);
  cvt_f32_bf16<<<(NDIS * 256 / 8 + 255) / 256, 256, 0, stream>>>(x_dis, p.xib1, NDIS * 256 / 8);

  // CSR build
  zero_ints<<<(NS_TOT + 255) / 256, 256, 0, stream>>>(p.counts, NS_TOT);
  dim3 ge((NE + 255) / 256, NREL);
  hist_k<<<ge, 256, 0, stream>>>(ri, p.counts);
  int nb = (NS_TOT + 1023) / 1024;
  scan_blk<<<nb, 256, 0, stream>>>(p.counts, p.cursor, p.bsum, NS_TOT);
  scan_top<<<1, 512, 0, stream>>>(p.bsum, nb);
  scan_add<<<(NS_TOT + 255) / 256, 256, 0, stream>>>(p.cursor, p.bsum, p.rowptr, p.cursor, NS_TOT);
  fill_k<<<ge, 256, 0, stream>>>(ri, p.cursor, p.colsrc);

  // Layer 1 (K=256, relu output)
  run_layer(p.xdb1, p.xib1, 256, W1s, W1d, a1s, a1d, b1, p.xd1b, p.xi1b, true, p, stream);
  // Layer 2 (K=128, no relu)
  run_layer(p.xd1b, p.xi1b, 128, W2s, W2d, a2s, a2d, b2, p.xd2b, p.xi2b, false, p, stream);

  // final linear + bias + relu -> d_out (f32)
  int4 r0 = make_int4(0, 0, 0, 0);
  build_wcatT<<<(128 * 128 + 255) / 256, 256, 0, stream>>>(Wdr, p.wfinT_d, 128, 128, r0);
  build_wcatT<<<(128 * 128 + 255) / 256, 256, 0, stream>>>(Wdi, p.wfinT_i, 128, 128, r0);
  float* out = (float*)d_out;
  mfma_gemm<true, true, false><<<dim3((NDRUG + 127) / 128, 1), 256, 0, stream>>>(
      p.xd2b, p.wfinT_d, bdr, out, NDRUG, 128, 128);
  mfma_gemm<true, true, false><<<dim3((NDIS + 127) / 128, 1), 256, 0, stream>>>(
      p.xi2b, p.wfinT_i, bdi, out + (size_t)NDRUG * HID, NDIS, 128, 128);
}

// Round 4
// 483.428 us; speedup vs baseline: 9.1328x; 1.1377x over previous
//
#include <hip/hip_runtime.h>
#include <stdint.h>

#define NDRUG 20000
#define NDIS  40000
#define HID   128
#define NE    150000
#define NREL  7
#define RPSTR (NDIS + 1)
#define NS_TOT (NREL * RPSTR)

typedef unsigned short ushort_t;
typedef __attribute__((ext_vector_type(8))) short bf16x8;
typedef __attribute__((ext_vector_type(4))) float f32x4;
typedef const __attribute__((address_space(1))) void gv_t;
typedef __attribute__((address_space(3))) void lv_t;

__device__ __forceinline__ ushort_t f2bf(float f) {
  unsigned u = __float_as_uint(f);
  u += 0x7FFFu + ((u >> 16) & 1u);          // RNE
  return (ushort_t)(u >> 16);
}
__device__ __forceinline__ float bf2f(ushort_t h) {
  return __uint_as_float(((unsigned)h) << 16);
}

// ================= bf16 MFMA GEMM: C[M,N] = A[M,K] @ BT[N,K]^T =================
// A,BT bf16 row-major. N multiple of 128, K multiple of 32. 128x128 tile, 4 waves.
// Staging via global_load_lds (16B), linear LDS rows of 32 bf16 (64B).
template<bool BIAS, bool RELU, bool BF16OUT>
__global__ __launch_bounds__(256) void mfma_gemm(
    const ushort_t* __restrict__ A, const ushort_t* __restrict__ BT,
    const float* __restrict__ bias, void* __restrict__ Cout, int M, int N, int K)
{
  __shared__ ushort_t As[128 * 32];
  __shared__ ushort_t Bs[128 * 32];
  const int tid = threadIdx.x;
  const int m0 = blockIdx.x * 128;
  const int n0 = blockIdx.y * 128;
  const int wave = tid >> 6, lane = tid & 63;
  const int wm = wave & 1, wn = wave >> 1;
  const int l15 = lane & 15, lk = lane >> 4;

  // staging map: issue i in {0,1}: flat = wave*64 + lane + 256*i
  // row = wave*16 + lane/4 + i*64 ; chunk = (lane&3)*8 ushorts (16B)
  const int rowS = wave * 16 + (lane >> 2);
  const int chunk = (lane & 3) * 8;
  const int grA0 = min(m0 + rowS, M - 1);
  const int grA1 = min(m0 + rowS + 64, M - 1);
  const int grB0 = n0 + rowS;
  const int grB1 = n0 + rowS + 64;
  const ushort_t* ga0 = A + (size_t)grA0 * K + chunk;
  const ushort_t* ga1 = A + (size_t)grA1 * K + chunk;
  const ushort_t* gb0 = BT + (size_t)grB0 * K + chunk;
  const ushort_t* gb1 = BT + (size_t)grB1 * K + chunk;

  f32x4 acc[4][4] = {};

  for (int k0 = 0; k0 < K; k0 += 32) {
    __syncthreads();   // all waves done reading LDS of previous step
    __builtin_amdgcn_global_load_lds((gv_t*)(ga0 + k0), (lv_t*)(As + wave * 512), 16, 0, 0);
    __builtin_amdgcn_global_load_lds((gv_t*)(ga1 + k0), (lv_t*)(As + wave * 512 + 2048), 16, 0, 0);
    __builtin_amdgcn_global_load_lds((gv_t*)(gb0 + k0), (lv_t*)(Bs + wave * 512), 16, 0, 0);
    __builtin_amdgcn_global_load_lds((gv_t*)(gb1 + k0), (lv_t*)(Bs + wave * 512 + 2048), 16, 0, 0);
    __syncthreads();   // compiler drains vmcnt before barrier -> tiles landed

    bf16x8 af[4], bfg[4];
    #pragma unroll
    for (int m = 0; m < 4; ++m)
      af[m] = *reinterpret_cast<const bf16x8*>(&As[(wm * 64 + m * 16 + l15) * 32 + lk * 8]);
    #pragma unroll
    for (int n = 0; n < 4; ++n)
      bfg[n] = *reinterpret_cast<const bf16x8*>(&Bs[(wn * 64 + n * 16 + l15) * 32 + lk * 8]);
    #pragma unroll
    for (int m = 0; m < 4; ++m)
      #pragma unroll
      for (int n = 0; n < 4; ++n)
        acc[m][n] = __builtin_amdgcn_mfma_f32_16x16x32_bf16(af[m], bfg[n], acc[m][n], 0, 0, 0);
  }

  #pragma unroll
  for (int m = 0; m < 4; ++m) {
    int rbase = m0 + wm * 64 + m * 16 + lk * 4;
    #pragma unroll
    for (int n = 0; n < 4; ++n) {
      int col = n0 + wn * 64 + n * 16 + l15;
      float bv = 0.f;
      if (BIAS) bv = bias[col];
      #pragma unroll
      for (int j = 0; j < 4; ++j) {
        int row = rbase + j;
        if (row >= M) continue;
        float v = acc[m][n][j] + bv;
        if (RELU) v = fmaxf(v, 0.f);
        if (BF16OUT) ((ushort_t*)Cout)[(size_t)row * N + col] = f2bf(v);
        else         ((float*)Cout)[(size_t)row * N + col] = v;
      }
    }
  }
}

// ================= weight prep =================
__global__ void build_wcatT(const float* __restrict__ W, ushort_t* __restrict__ out,
                            int K, int ncol, int4 rels)
{
  int id = blockIdx.x * 256 + threadIdx.x;
  int tot = K * ncol;
  if (id >= tot) return;
  int k = id / ncol, c = id - k * ncol;
  int rr = (&rels.x)[c >> 7];
  out[(size_t)c * K + k] = f2bf(W[((size_t)rr * K + k) * HID + (c & 127)]);
}

// wv[slot][k] = sum_j W[r][k][j] * a[r][j]   (slot<7: src, else dst)
__global__ __launch_bounds__(256) void wvec_kernel(
    const float* __restrict__ Wsrc, const float* __restrict__ as_,
    const float* __restrict__ Wdst, const float* __restrict__ ad_,
    float* __restrict__ wv, int K)
{
  int slot = blockIdx.x;
  int r = slot % NREL;
  const float* W = (slot < NREL ? Wsrc : Wdst) + (size_t)r * K * HID;
  const float* a = (slot < NREL ? as_ : ad_) + r * HID;
  int wave = threadIdx.x >> 6, lane = threadIdx.x & 63;
  int k = blockIdx.y * 4 + wave;
  if (k >= K) return;
  float s = W[(size_t)k * HID + lane] * a[lane]
          + W[(size_t)k * HID + 64 + lane] * a[64 + lane];
  #pragma unroll
  for (int off = 32; off; off >>= 1) s += __shfl_xor(s, off);
  if (lane == 0) wv[slot * 256 + k] = s;
}

// ================= f32 -> bf16 convert =================
__global__ void cvt_f32_bf16(const float* __restrict__ in, ushort_t* __restrict__ out, int n8) {
  int i = blockIdx.x * 256 + threadIdx.x;
  if (i >= n8) return;
  float4 a = reinterpret_cast<const float4*>(in)[2 * i];
  float4 b = reinterpret_cast<const float4*>(in)[2 * i + 1];
  ushort_t r[8] = {f2bf(a.x), f2bf(a.y), f2bf(a.z), f2bf(a.w),
                   f2bf(b.x), f2bf(b.y), f2bf(b.z), f2bf(b.w)};
  reinterpret_cast<uint4*>(out)[i] = *reinterpret_cast<uint4*>(r);
}

// ================= batched alpha GEMV (bf16 X) =================
struct AlphaJobs { int wslot[8]; int outOff[8]; };

template<int NV, int K>
__global__ __launch_bounds__(256) void alpha_batch(
    const ushort_t* __restrict__ X, int N, const float* __restrict__ wv,
    float* __restrict__ outBase, AlphaJobs jobs)
{
  int i = blockIdx.x * 256 + threadIdx.x;
  if (i >= N) return;
  float acc[NV];
  #pragma unroll
  for (int v = 0; v < NV; ++v) acc[v] = 0.f;
  const ushort_t* xp = X + (size_t)i * K;
  for (int k = 0; k < K; k += 8) {
    uint4 u = *reinterpret_cast<const uint4*>(xp + k);
    unsigned uu[4] = {u.x, u.y, u.z, u.w};
    float xf[8];
    #pragma unroll
    for (int q = 0; q < 4; ++q) {
      xf[2 * q]     = __uint_as_float(uu[q] << 16);
      xf[2 * q + 1] = __uint_as_float(uu[q] & 0xFFFF0000u);
    }
    #pragma unroll
    for (int v = 0; v < NV; ++v) {
      const float* wp = wv + jobs.wslot[v] * 256 + k;
      #pragma unroll
      for (int q = 0; q < 8; ++q) acc[v] += xf[q] * wp[q];
    }
  }
  #pragma unroll
  for (int v = 0; v < NV; ++v) outBase[jobs.outOff[v] + i] = acc[v];
}

// ================= CSR build =================
struct RelIdx { const int* src[NREL]; const int* dst[NREL]; };
struct NdArr  { int nd[NREL]; };

__global__ void zero_ints(int* __restrict__ p, int n) {
  int i = blockIdx.x * 256 + threadIdx.x;
  if (i < n) p[i] = 0;
}
__global__ void hist_k(RelIdx ri, int* __restrict__ counts) {
  int e = blockIdx.x * 256 + threadIdx.x;
  int r = blockIdx.y;
  if (e >= NE) return;
  atomicAdd(&counts[r * RPSTR + ri.dst[r][e]], 1);
}
__global__ __launch_bounds__(256) void scan_blk(const int* __restrict__ in,
                                                int* __restrict__ partial,
                                                int* __restrict__ bsum, int n)
{
  __shared__ int ts[256];
  int t = threadIdx.x;
  int base = blockIdx.x * 1024 + t * 4;
  int v[4];
  #pragma unroll
  for (int i = 0; i < 4; ++i) v[i] = (base + i < n) ? in[base + i] : 0;
  int s = v[0] + v[1] + v[2] + v[3];
  ts[t] = s; __syncthreads();
  for (int off = 1; off < 256; off <<= 1) {
    int x = (t >= off) ? ts[t - off] : 0;
    __syncthreads();
    ts[t] += x;
    __syncthreads();
  }
  int run = ts[t] - s;
  #pragma unroll
  for (int i = 0; i < 4; ++i) {
    if (base + i < n) partial[base + i] = run;
    run += v[i];
  }
  if (t == 255) bsum[blockIdx.x] = ts[255];
}
__global__ __launch_bounds__(512) void scan_top(int* __restrict__ bsum, int nb) {
  __shared__ int ts[512];
  int t = threadIdx.x;
  int v = (t < nb) ? bsum[t] : 0;
  ts[t] = v; __syncthreads();
  for (int off = 1; off < 512; off <<= 1) {
    int x = (t >= off) ? ts[t - off] : 0;
    __syncthreads();
    ts[t] += x;
    __syncthreads();
  }
  if (t < nb) bsum[t] = ts[t] - v;
}
__global__ void scan_add(const int* __restrict__ partial, const int* __restrict__ bsum,
                         int* __restrict__ rowptr, int* __restrict__ cursor, int n)
{
  int i = blockIdx.x * 256 + threadIdx.x;
  if (i >= n) return;
  int v = partial[i] + bsum[i >> 10];
  rowptr[i] = v; cursor[i] = v;
}
__global__ void fill_k(RelIdx ri, int* __restrict__ cursor, int* __restrict__ colsrc) {
  int e = blockIdx.x * 256 + threadIdx.x;
  int r = blockIdx.y;
  if (e >= NE) return;
  int d = ri.dst[r][e];
  int pos = atomicAdd(&cursor[r * RPSTR + d], 1);
  colsrc[pos] = ri.src[r][e];
}

// ================= per-(rel,dst) softmax -> normalized coef[e] =================
__global__ __launch_bounds__(256) void coef_k(
    const int* __restrict__ rowptr, const int* __restrict__ colsrc,
    const float* __restrict__ alphaB, float* __restrict__ coef, NdArr nds)
{
  int d = blockIdx.x * 256 + threadIdx.x;
  int r = blockIdx.y;
  if (d >= nds.nd[r]) return;
  int beg = rowptr[r * RPSTR + d], end = rowptr[r * RPSTR + d + 1];
  if (beg == end) return;
  const float ad = alphaB[(NREL + r) * NDIS + d];
  const float* as = alphaB + (size_t)r * NDIS;
  float m = -1e30f;
  for (int i = beg; i < end; ++i) {
    float a = as[colsrc[i]] + ad;
    a = a > 0.f ? a : 0.2f * a;
    m = fmaxf(m, a);
  }
  float sum = 0.f;
  for (int i = beg; i < end; ++i) {
    float a = as[colsrc[i]] + ad;
    a = a > 0.f ? a : 0.2f * a;
    float ex = __expf(a - m);
    coef[i] = ex;
    sum += ex;
  }
  float inv = 1.f / (sum + 1e-16f);
  for (int i = beg; i < end; ++i) coef[i] *= inv;
}

// ================= pure weighted gather PV (wave per dst, both types) =================
struct PvRel { int rel; int rowptr_off; const ushort_t* hs; int hst; int hoff; };
struct PvParams { PvRel dr[3]; PvRel di[4]; };

template<bool RELU>
__global__ __launch_bounds__(256) void pv_multi(
    PvParams P, const int* __restrict__ rowptr, const int* __restrict__ colsrc,
    const float* __restrict__ coef, const float* __restrict__ bias,
    ushort_t* __restrict__ outD, ushort_t* __restrict__ outI, int nbD)
{
  const int wave = threadIdx.x >> 6, lane = threadIdx.x & 63;
  const int c0 = lane * 2;
  const bool isD = blockIdx.x < (unsigned)nbD;
  const int d = (isD ? blockIdx.x : blockIdx.x - nbD) * 4 + wave;
  const int Nd = isD ? NDRUG : NDIS;
  if (d >= Nd) return;
  const int nr = isD ? 3 : 4;
  float acc0 = 0.f, acc1 = 0.f;

  for (int q = 0; q < nr; ++q) {
    const PvRel R = isD ? P.dr[q] : P.di[q];
    acc0 += bias[R.rel * HID + c0];
    acc1 += bias[R.rel * HID + c0 + 1];
    const int beg = rowptr[R.rowptr_off + d];
    const int end = rowptr[R.rowptr_off + d + 1];
    const ushort_t* hsb = R.hs + R.hoff + c0;
    const int hst = R.hst;
    for (int c = beg; c < end; c += 4) {
      float cf[4]; int si[4];
      #pragma unroll
      for (int j = 0; j < 4; ++j) {
        int idx = (c + j < end) ? c + j : end - 1;
        cf[j] = (c + j < end) ? coef[idx] : 0.f;
        si[j] = colsrc[idx];
      }
      ushort2 hv[4];
      #pragma unroll
      for (int j = 0; j < 4; ++j)
        hv[j] = *reinterpret_cast<const ushort2*>(hsb + (size_t)si[j] * hst);
      #pragma unroll
      for (int j = 0; j < 4; ++j) {
        acc0 += cf[j] * bf2f(hv[j].x);
        acc1 += cf[j] * bf2f(hv[j].y);
      }
    }
  }
  if (RELU) { acc0 = fmaxf(acc0, 0.f); acc1 = fmaxf(acc1, 0.f); }
  ushort_t* out = isD ? outD : outI;
  ushort2 o; o.x = f2bf(acc0); o.y = f2bf(acc1);
  *reinterpret_cast<ushort2*>(out + (size_t)d * HID + c0) = o;
}

// ================= host =================
struct WsPlan {
  ushort_t *xdb1, *xib1, *xd1b, *xi1b, *xd2b, *xi2b;
  ushort_t *hs_d, *hs_i, *wcatT_d, *wcatT_i, *wfinT_d, *wfinT_i;
  float *alphaB, *wv, *coef;
  int *counts, *rowptr, *cursor, *colsrc, *bsum;
  size_t total_bytes;
};

static WsPlan plan_ws(void* d_ws) {
  WsPlan p;
  ushort_t* s = (ushort_t*)d_ws;
  p.xdb1 = s;     s += (size_t)NDRUG * 256;
  p.xib1 = s;     s += (size_t)NDIS * 256;
  p.xd1b = s;     s += (size_t)NDRUG * HID;
  p.xi1b = s;     s += (size_t)NDIS * HID;
  p.hs_d = s;     s += (size_t)NDRUG * 384;
  p.hs_i = s;     s += (size_t)NDIS * 512;
  p.wcatT_d = s;  s += 384 * 256;
  p.wcatT_i = s;  s += 512 * 256;
  p.wfinT_d = s;  s += 128 * 128;
  p.wfinT_i = s;  s += 128 * 128;
  p.xd2b = p.xdb1;   // alias: xdb1 dead after L1 GEMM/alpha
  p.xi2b = p.xib1;
  float* f = (float*)s;
  p.alphaB = f;   f += (size_t)2 * NREL * NDIS;
  p.wv = f;       f += 14 * 256;
  p.coef = f;     f += (size_t)NREL * NE;
  int* q = (int*)f;
  p.counts = q;   q += NS_TOT;
  p.rowptr = q;   q += NS_TOT;
  p.cursor = q;   q += NS_TOT;
  p.colsrc = q;   q += NREL * NE;
  p.bsum = q;     q += 512;
  p.total_bytes = (size_t)((char*)q - (char*)d_ws);
  return p;
}

static void run_layer(const ushort_t* XDb, const ushort_t* XIb, int K,
                      const float* Wsrc, const float* Wdst,
                      const float* as_, const float* ad_, const float* bias,
                      ushort_t* outDb, ushort_t* outIb, bool relu,
                      const WsPlan& p, hipStream_t stream)
{
  int4 rd = make_int4(0, 2, 6, 0);
  int4 ri4 = make_int4(1, 3, 4, 5);
  build_wcatT<<<(K * 384 + 255) / 256, 256, 0, stream>>>(Wsrc, p.wcatT_d, K, 384, rd);
  build_wcatT<<<(K * 512 + 255) / 256, 256, 0, stream>>>(Wsrc, p.wcatT_i, K, 512, ri4);
  wvec_kernel<<<dim3(14, K / 4), 256, 0, stream>>>(Wsrc, as_, Wdst, ad_, p.wv, K);

  AlphaJobs jd = {};
  jd.wslot[0] = 0;     jd.outOff[0] = 0 * NDIS;
  jd.wslot[1] = 2;     jd.outOff[1] = 2 * NDIS;
  jd.wslot[2] = 6;     jd.outOff[2] = 6 * NDIS;
  jd.wslot[3] = 7 + 1; jd.outOff[3] = (7 + 1) * NDIS;
  jd.wslot[4] = 7 + 3; jd.outOff[4] = (7 + 3) * NDIS;
  jd.wslot[5] = 7 + 6; jd.outOff[5] = (7 + 6) * NDIS;
  AlphaJobs ji = {};
  ji.wslot[0] = 1;     ji.outOff[0] = 1 * NDIS;
  ji.wslot[1] = 3;     ji.outOff[1] = 3 * NDIS;
  ji.wslot[2] = 4;     ji.outOff[2] = 4 * NDIS;
  ji.wslot[3] = 5;     ji.outOff[3] = 5 * NDIS;
  ji.wslot[4] = 7 + 0; ji.outOff[4] = (7 + 0) * NDIS;
  ji.wslot[5] = 7 + 2; ji.outOff[5] = (7 + 2) * NDIS;
  ji.wslot[6] = 7 + 4; ji.outOff[6] = (7 + 4) * NDIS;
  ji.wslot[7] = 7 + 5; ji.outOff[7] = (7 + 5) * NDIS;
  int gbD = (NDRUG + 255) / 256, gbI = (NDIS + 255) / 256;
  if (K == 256) {
    alpha_batch<6, 256><<<gbD, 256, 0, stream>>>(XDb, NDRUG, p.wv, p.alphaB, jd);
    alpha_batch<8, 256><<<gbI, 256, 0, stream>>>(XIb, NDIS, p.wv, p.alphaB, ji);
  } else {
    alpha_batch<6, 128><<<gbD, 256, 0, stream>>>(XDb, NDRUG, p.wv, p.alphaB, jd);
    alpha_batch<8, 128><<<gbI, 256, 0, stream>>>(XIb, NDIS, p.wv, p.alphaB, ji);
  }

  // hs GEMMs (bf16 out)
  mfma_gemm<false, false, true><<<dim3((NDRUG + 127) / 128, 3), 256, 0, stream>>>(
      XDb, p.wcatT_d, nullptr, p.hs_d, NDRUG, 384, K);
  mfma_gemm<false, false, true><<<dim3((NDIS + 127) / 128, 4), 256, 0, stream>>>(
      XIb, p.wcatT_i, nullptr, p.hs_i, NDIS, 512, K);

  // softmax coefs (per (rel,dst) thread)
  NdArr nds;
  static const int DSTh[NREL] = {1, 0, 1, 0, 1, 1, 0};
  for (int r = 0; r < NREL; ++r) nds.nd[r] = DSTh[r] == 0 ? NDRUG : NDIS;
  coef_k<<<dim3((NDIS + 255) / 256, NREL), 256, 0, stream>>>(
      p.rowptr, p.colsrc, p.alphaB, p.coef, nds);

  // fused PV gather (one dispatch, both dst types)
  PvParams P;
  P.dr[0] = {1, 1 * RPSTR, p.hs_i, 512, 0};
  P.dr[1] = {3, 3 * RPSTR, p.hs_i, 512, 128};
  P.dr[2] = {6, 6 * RPSTR, p.hs_d, 384, 256};
  P.di[0] = {0, 0 * RPSTR, p.hs_d, 384, 0};
  P.di[1] = {2, 2 * RPSTR, p.hs_d, 384, 128};
  P.di[2] = {4, 4 * RPSTR, p.hs_i, 512, 256};
  P.di[3] = {5, 5 * RPSTR, p.hs_i, 512, 384};
  int nbD = (NDRUG + 3) / 4, nbI = (NDIS + 3) / 4;
  if (relu)
    pv_multi<true><<<nbD + nbI, 256, 0, stream>>>(
        P, p.rowptr, p.colsrc, p.coef, bias, outDb, outIb, nbD);
  else
    pv_multi<false><<<nbD + nbI, 256, 0, stream>>>(
        P, p.rowptr, p.colsrc, p.coef, bias, outDb, outIb, nbD);
}

extern "C" void kernel_launch(void* const* d_in, const int* in_sizes, int n_in,
                              void* d_out, int out_size, void* d_ws, size_t ws_size,
                              hipStream_t stream) {
  const float* x_drug = (const float*)d_in[0];
  const float* x_dis  = (const float*)d_in[1];
  RelIdx ri;
  for (int r = 0; r < NREL; ++r) {
    const int* e = (const int*)d_in[2 + r];
    ri.src[r] = e; ri.dst[r] = e + NE;
  }
  const float* W1s = (const float*)d_in[9];
  const float* W1d = (const float*)d_in[10];
  const float* a1s = (const float*)d_in[11];
  const float* a1d = (const float*)d_in[12];
  const float* b1  = (const float*)d_in[13];
  const float* W2s = (const float*)d_in[14];
  const float* W2d = (const float*)d_in[15];
  const float* a2s = (const float*)d_in[16];
  const float* a2d = (const float*)d_in[17];
  const float* b2  = (const float*)d_in[18];
  const float* Wdr = (const float*)d_in[19];
  const float* bdr = (const float*)d_in[20];
  const float* Wdi = (const float*)d_in[21];
  const float* bdi = (const float*)d_in[22];

  WsPlan p = plan_ws(d_ws);
  if (p.total_bytes > ws_size) return;

  cvt_f32_bf16<<<(NDRUG * 256 / 8 + 255) / 256, 256, 0, stream>>>(x_drug, p.xdb1, NDRUG * 256 / 8);
  cvt_f32_bf16<<<(NDIS * 256 / 8 + 255) / 256, 256, 0, stream>>>(x_dis, p.xib1, NDIS * 256 / 8);

  // CSR build
  zero_ints<<<(NS_TOT + 255) / 256, 256, 0, stream>>>(p.counts, NS_TOT);
  dim3 ge((NE + 255) / 256, NREL);
  hist_k<<<ge, 256, 0, stream>>>(ri, p.counts);
  int nb = (NS_TOT + 1023) / 1024;
  scan_blk<<<nb, 256, 0, stream>>>(p.counts, p.cursor, p.bsum, NS_TOT);
  scan_top<<<1, 512, 0, stream>>>(p.bsum, nb);
  scan_add<<<(NS_TOT + 255) / 256, 256, 0, stream>>>(p.cursor, p.bsum, p.rowptr, p.cursor, NS_TOT);
  fill_k<<<ge, 256, 0, stream>>>(ri, p.cursor, p.colsrc);

  // Layer 1 (K=256, relu), Layer 2 (K=128)
  run_layer(p.xdb1, p.xib1, 256, W1s, W1d, a1s, a1d, b1, p.xd1b, p.xi1b, true, p, stream);
  run_layer(p.xd1b, p.xi1b, 128, W2s, W2d, a2s, a2d, b2, p.xd2b, p.xi2b, false, p, stream);

  // final linear + bias + relu -> d_out (f32)
  int4 r0 = make_int4(0, 0, 0, 0);
  build_wcatT<<<(128 * 128 + 255) / 256, 256, 0, stream>>>(Wdr, p.wfinT_d, 128, 128, r0);
  build_wcatT<<<(128 * 128 + 255) / 256, 256, 0, stream>>>(Wdi, p.wfinT_i, 128, 128, r0);
  float* out = (float*)d_out;
  mfma_gemm<true, true, false><<<dim3((NDRUG + 127) / 128, 1), 256, 0, stream>>>(
      p.xd2b, p.wfinT_d, bdr, out, NDRUG, 128, 128);
  mfma_gemm<true, true, false><<<dim3((NDIS + 127) / 128, 1), 256, 0, stream>>>(
      p.xi2b, p.wfinT_i, bdi, out + (size_t)NDRUG * HID, NDIS, 128, 128);
}